// Round 6
// baseline (1101.320 us; speedup 1.0000x reference)
//
#include <hip/hip_runtime.h>
#include <stdint.h>

// Problem constants
#define BATCH 16
#define NPTS 4096
#define DFEAT 128
#define NGRP 1024
#define KNNK 16
#define DOUT_CH 256
#define KPAD 160          // 131 padded to 5*32 for MFMA K
#define APAD 168          // LDS row stride (pad for banks)
#define NGROUPS (BATCH*NGRP)            // 16384
#define MROWS (NGROUPS*KNNK)            // 262144
#define NWORKERS 240
#define NCHUNKS (NGROUPS/8)             // 2048 chunks of 8 groups
#define CHUNKS_PER_BATCH (NGRP/8)       // 128
#define OUT_FEAT_ELEMS (NGROUPS*DOUT_CH) // 4194304
#define KNN_SLOTS 512

typedef __attribute__((ext_vector_type(8))) short s16x8;
typedef __attribute__((ext_vector_type(8))) __bf16 bf16x8;
typedef __attribute__((ext_vector_type(4))) float f32x4;

union V8U { s16x8 s; bf16x8 b; };

__device__ inline unsigned short f2bf(float f) {
  unsigned u = __float_as_uint(f);
  unsigned r = 0x7FFFu + ((u >> 16) & 1u);
  return (unsigned short)((u + r) >> 16);
}

// Bit-exact (vs fp32 numpy ref, no-FMA) squared distance: ((dx*dx + dy*dy) + dz*dz)
__device__ inline float sqdist3(float ax, float ay, float az,
                                float bx, float by, float bz) {
  float dx = __fsub_rn(ax, bx);
  float dy = __fsub_rn(ay, by);
  float dz = __fsub_rn(az, bz);
  return __fadd_rn(__fadd_rn(__fmul_rn(dx, dx), __fmul_rn(dy, dy)), __fmul_rn(dz, dz));
}

__device__ inline unsigned long long u64max(unsigned long long a, unsigned long long b) {
  return a > b ? a : b;
}

// DPP max step (bound_ctrl=true: invalid lanes read 0; 0 never wins a max of keys>0)
template<int CTRL>
__device__ inline unsigned long long dpp_max_step(unsigned long long k) {
  unsigned hi = (unsigned)(k >> 32), lo = (unsigned)k;
  unsigned hi2 = (unsigned)__builtin_amdgcn_update_dpp(0, (int)hi, CTRL, 0xF, 0xF, true);
  unsigned lo2 = (unsigned)__builtin_amdgcn_update_dpp(0, (int)lo, CTRL, 0xF, 0xF, true);
  unsigned long long k2 = ((unsigned long long)hi2 << 32) | lo2;
  return k2 > k ? k2 : k;
}
__device__ inline unsigned long long wave_max_u64(unsigned long long k) {
  k = dpp_max_step<0xB1>(k);
  k = dpp_max_step<0x4E>(k);
  k = dpp_max_step<0x141>(k);
  k = dpp_max_step<0x140>(k);
  k = dpp_max_step<0x142>(k);
  k = dpp_max_step<0x143>(k);
  return k;   // lane 63 holds max
}

// DPP min step (bound_ctrl=false, old=self: invalid lanes keep own key -> harmless for min)
template<int CTRL>
__device__ inline unsigned long long dpp_min_step(unsigned long long k) {
  unsigned hi = (unsigned)(k >> 32), lo = (unsigned)k;
  unsigned hi2 = (unsigned)__builtin_amdgcn_update_dpp((int)hi, (int)hi, CTRL, 0xF, 0xF, false);
  unsigned lo2 = (unsigned)__builtin_amdgcn_update_dpp((int)lo, (int)lo, CTRL, 0xF, 0xF, false);
  unsigned long long k2 = ((unsigned long long)hi2 << 32) | lo2;
  return k2 < k ? k2 : k;
}
__device__ inline unsigned long long wave_min_u64(unsigned long long k) {
  k = dpp_min_step<0xB1>(k);
  k = dpp_min_step<0x4E>(k);
  k = dpp_min_step<0x141>(k);
  k = dpp_min_step<0x140>(k);
  k = dpp_min_step<0x142>(k);
  k = dpp_min_step<0x143>(k);
  return k;   // lane 63 holds min
}

// Shared-memory union: FPS role vs worker role. sizeof ~91-94 KB on both paths
// => strictly 1 block/CU (2x93KB > 160KB), 256 blocks <= 256 CUs, all resident.
struct FpsSh {
  float4 c4[NPTS];                 // 64 KB
  float ocb[NGRP * 3];             // 12 KB
  unsigned long long slots[2][4];  // double-buffered per-wave winners
};
struct WrkSh {
  float wd[4][NPTS];               // 64 KB per-wave dist caches
  float svd[4][KNN_SLOTS];         // 8 KB
  int   svi[4][KNN_SLOTS];         // 8 KB
  unsigned short Abuf[2][16][APAD];// 10.5 KB
  int   nidx_s[8][KNNK];           // 512 B
  float cent_s[8][3];              // staged centers
};
union ShU { FpsSh f; WrkSh w; };

// ---------------------------------------------------------------------------
// Fused producer-consumer kernel.
// Blocks 0..15: FPS per batch; publish centers in chunks of 8 (plain stores +
//   threadfence + agent release on progress[b]).
// Blocks 16..255: workers. Block 16 additionally casts W->Wb first and
//   releases wb_ready. Workers claim chunks statically (wi, wi+240, ...):
//   spin on progress, then kNN (wave-local) + MFMA GEMM for 8 groups.
// ---------------------------------------------------------------------------
__global__ __launch_bounds__(256)
void fused_kernel(const float* __restrict__ feat, const float* __restrict__ coord,
                  const float* __restrict__ W, float* __restrict__ out_coord,
                  unsigned short* __restrict__ Wb,
                  float* __restrict__ psum, float* __restrict__ psumsq,
                  float* __restrict__ wmax, float* __restrict__ wmin,
                  int* __restrict__ progress, int* __restrict__ wb_ready)
{
  __shared__ ShU sh;
  const int tid = threadIdx.x;
  const int w = tid >> 6;
  const int lane = tid & 63;

  if (blockIdx.x < BATCH) {
    // ------------------------- FPS producer role -------------------------
    const int b = blockIdx.x;
    float4* c4 = sh.f.c4;
    float* ocb = sh.f.ocb;

    const float* g = coord + (size_t)b * NPTS * 3;
    for (int p = tid; p < NPTS; p += 256)
      c4[p] = make_float4(g[3 * p], g[3 * p + 1], g[3 * p + 2], 0.f);
    __syncthreads();

    float px[16], py[16], pz[16], dist[16];
    unsigned lokey[16];
    #pragma unroll
    for (int j = 0; j < 16; ++j) {
      int p = tid + 256 * j;
      float4 c = c4[p];
      px[j] = c.x; py[j] = c.y; pz[j] = c.z;
      dist[j] = __builtin_inff();
      lokey[j] = 0xFFFFFFFFu - (unsigned)p;      // bigger lo == smaller idx
    }

    float lx = c4[0].x, ly = c4[0].y, lz = c4[0].z;
    if (tid == 0) { ocb[0] = lx; ocb[1] = ly; ocb[2] = lz; }

    float* oc = out_coord + (size_t)b * NGRP * 3;
    int pend = 0;

    for (int i = 1; i < NGRP; ++i) {
      const int par = i & 1;
      unsigned long long cand[16];
      #pragma unroll
      for (int j = 0; j < 16; ++j) {
        float d  = sqdist3(px[j], py[j], pz[j], lx, ly, lz);
        float nd = fminf(dist[j], d);
        dist[j] = nd;
        cand[j] = ((unsigned long long)__float_as_uint(nd) << 32) | lokey[j];
      }
      #pragma unroll
      for (int st = 8; st >= 1; st >>= 1)
        #pragma unroll
        for (int j = 0; j < st; ++j)
          cand[j] = u64max(cand[j], cand[j + st]);
      unsigned long long best = wave_max_u64(cand[0]);
      if (lane == 63) sh.f.slots[par][w] = best;
      __syncthreads();

      // publish: stores issued 1 iter ago are drained by the barrier above
      if (pend) {
        if (tid == 0) {
          __threadfence();
          __hip_atomic_store(&progress[b], pend, __ATOMIC_RELEASE, __HIP_MEMORY_SCOPE_AGENT);
        }
        pend = 0;
      }
      if ((i & 7) == 0) {                    // i = 8,16,...,1016
        if (tid < 24) oc[(i - 8) * 3 + tid] = ocb[(i - 8) * 3 + tid];
        pend = i;
      }

      unsigned long long s0 = u64max(sh.f.slots[par][0], sh.f.slots[par][1]);
      unsigned long long s1 = u64max(sh.f.slots[par][2], sh.f.slots[par][3]);
      unsigned long long f = u64max(s0, s1);
      int mi = (int)(0xFFFFFFFFu - (unsigned)(f & 0xFFFFFFFFull));

      float4 cw = c4[mi];
      lx = cw.x; ly = cw.y; lz = cw.z;
      if (tid < 3) ocb[3 * i + tid] = (tid == 0) ? cw.x : ((tid == 1) ? cw.y : cw.z);
    }

    __syncthreads();
    #pragma unroll
    for (int qq = 0; qq < 12; ++qq) oc[tid + 256 * qq] = ocb[tid + 256 * qq];
    __syncthreads();
    if (tid == 0) {
      __threadfence();
      __hip_atomic_store(&progress[b], NGRP, __ATOMIC_RELEASE, __HIP_MEMORY_SCOPE_AGENT);
    }
    return;
  }

  // --------------------------- worker role ---------------------------
  const int wi = blockIdx.x - BATCH;

  if (wi == 0) {
    // W: [256][131] fp32 -> Wb: [256][160] bf16 (cols 0..127 = W[:,3:131],
    // 128..130 = W[:,0:3], 131..159 = 0)
    for (int i = tid; i < DOUT_CH * KPAD; i += 256) {
      int n = i / KPAD;
      int k = i - n * KPAD;
      float v = 0.f;
      if (k < 128)      v = W[n * 131 + 3 + k];
      else if (k < 131) v = W[n * 131 + (k - 128)];
      Wb[i] = f2bf(v);
    }
    __syncthreads();
    if (tid == 0) {
      __threadfence();
      __hip_atomic_store(wb_ready, 1, __ATOMIC_RELEASE, __HIP_MEMORY_SCOPE_AGENT);
    }
  }
  // wait for Wb
  if (tid == 0) {
    while (__hip_atomic_load(wb_ready, __ATOMIC_RELAXED, __HIP_MEMORY_SCOPE_AGENT) == 0)
      __builtin_amdgcn_s_sleep(1);
    __threadfence();
  }
  __syncthreads();

  const int lr = lane & 15, q = lane >> 4;

  // B fragments in registers (held across all chunks)
  V8U bfrag[4][5];
  #pragma unroll
  for (int nt = 0; nt < 4; ++nt)
    #pragma unroll
    for (int kt = 0; kt < 5; ++kt) {
      int n = w * 64 + nt * 16 + lr;
      bfrag[nt][kt].s = *(const s16x8*)(Wb + n * KPAD + kt * 32 + q * 8);
    }

  // zero pad cols 128..159 of both Abuf buffers once
  for (int i = tid; i < 2 * 16 * 32; i += 256) {
    int buf = i >> 9, rr = (i >> 5) & 15, cc = 128 + (i & 31);
    sh.w.Abuf[buf][rr][cc] = 0;
  }
  float sum1[4] = {0, 0, 0, 0}, sum2[4] = {0, 0, 0, 0};
  __syncthreads();

  for (int c = wi; c < NCHUNKS; c += NWORKERS) {
    const int b = c >> 7;               // CHUNKS_PER_BATCH = 128
    const int lc = c & (CHUNKS_PER_BATCH - 1);
    const int need = lc * 8 + 8;

    if (tid == 0) {
      while (__hip_atomic_load(&progress[b], __ATOMIC_RELAXED, __HIP_MEMORY_SCOPE_AGENT) < need)
        __builtin_amdgcn_s_sleep(8);
      __threadfence();                  // acquire: invalidate caches
    }
    __syncthreads();

    // stage the 8 centers of this chunk
    if (tid < 24) sh.w.cent_s[tid / 3][tid % 3] =
        out_coord[(size_t)b * NGRP * 3 + lc * 24 + tid];
    __syncthreads();

    // ---- kNN (wave-local, no block barriers): wave w does centers 2w, 2w+1
    const float* pc = coord + (size_t)b * NPTS * 3;
    for (int k2 = 0; k2 < 2; ++k2) {
      const int k8 = w * 2 + k2;
      const float cx = sh.w.cent_s[k8][0], cy = sh.w.cent_s[k8][1], cz = sh.w.cent_s[k8][2];
      float* wd  = sh.w.wd[w];
      float* wsd = sh.w.svd[w];
      int*   wsi = sh.w.svi[w];

      float m = __builtin_inff();
      for (int tt = 0; tt < 64; ++tt) {
        int p = tt * 64 + lane;
        float d = sqdist3(cx, cy, cz, pc[3 * p], pc[3 * p + 1], pc[3 * p + 2]);
        wd[p] = d;
        m = fminf(m, d);
      }
      // T = 16th-smallest of per-lane minima (upper bound on true 16th dist)
      unsigned mb = __float_as_uint(m);
      unsigned prefix = 0u;
      for (int bit = 30; bit >= 0; --bit) {
        unsigned trial = prefix | (1u << bit);
        if (__popcll(__ballot(mb < trial)) < 16) prefix = trial;
      }
      const unsigned T = prefix;

      // compact survivors (slot order == ascending point idx)
      int base = 0;
      unsigned long long ltmask = (1ull << lane) - 1ull;
      for (int tt = 0; tt < 64; ++tt) {
        int p = tt * 64 + lane;
        float d = wd[p];
        bool keep = (__float_as_uint(d) <= T);
        unsigned long long mk = __ballot(keep);
        if (keep) {
          int pos = base + __popcll(mk & ltmask);
          if (pos < KNN_SLOTS) { wsd[pos] = d; wsi[pos] = p; }
        }
        base += __popcll(mk);
      }
      int S = base < KNN_SLOTS ? base : KNN_SLOTS;

      // register-resident survivors: lane owns slots lane+64k
      float rsd[8];
      #pragma unroll
      for (int k = 0; k < 8; ++k) {
        int s = lane + 64 * k;
        rsd[k] = (s < S) ? wsd[s] : __builtin_inff();
      }
      // 16 exact argmin rounds; u64-min key = (dbits<<32)|slot (lowest idx tie-break)
      for (int r = 0; r < KNNK; ++r) {
        unsigned long long key = 0xFFFFFFFFFFFFFFFFull;
        #pragma unroll
        for (int k = 0; k < 8; ++k) {
          unsigned long long kk = ((unsigned long long)__float_as_uint(rsd[k]) << 32)
                                | (unsigned)(lane + 64 * k);
          key = kk < key ? kk : key;
        }
        key = wave_min_u64(key);
        int bs = __builtin_amdgcn_readlane((int)(unsigned)(key & 0xFFFFFFFFull), 63);
        #pragma unroll
        for (int k = 0; k < 8; ++k)
          if (lane == (bs & 63) && k == (bs >> 6)) rsd[k] = __builtin_inff();
        if (lane == 0) sh.w.nidx_s[k8][r] = wsi[bs];
      }
    }
    __syncthreads();

    // ---- GEMM for the 8 groups of this chunk
    auto stage = [&](int gi, int buf) {
      int r = tid >> 4, c16 = tid & 15;
      int np = sh.w.nidx_s[gi][r];
      const float* fr = feat + ((size_t)(b * NPTS + np)) * DFEAT + c16 * 8;
      float4 f0 = ((const float4*)fr)[0];
      float4 f1 = ((const float4*)fr)[1];
      s16x8 v;
      v[0] = f2bf(f0.x); v[1] = f2bf(f0.y); v[2] = f2bf(f0.z); v[3] = f2bf(f0.w);
      v[4] = f2bf(f1.x); v[5] = f2bf(f1.y); v[6] = f2bf(f1.z); v[7] = f2bf(f1.w);
      *(s16x8*)&sh.w.Abuf[buf][r][c16 * 8] = v;
      if (tid < 16) {
        int np2 = sh.w.nidx_s[gi][tid];
        const float* p = coord + ((size_t)(b * NPTS + np2)) * 3;
        sh.w.Abuf[buf][tid][128] = f2bf(p[0] - sh.w.cent_s[gi][0]);
        sh.w.Abuf[buf][tid][129] = f2bf(p[1] - sh.w.cent_s[gi][1]);
        sh.w.Abuf[buf][tid][130] = f2bf(p[2] - sh.w.cent_s[gi][2]);
      }
    };

    stage(0, 0);
    __syncthreads();

    for (int gi = 0; gi < 8; ++gi) {
      int cur = gi & 1;
      if (gi < 7) stage(gi + 1, cur ^ 1);

      f32x4 acc[4];
      #pragma unroll
      for (int nt = 0; nt < 4; ++nt) acc[nt] = (f32x4)0.0f;
      #pragma unroll
      for (int kt = 0; kt < 5; ++kt) {
        V8U a;
        a.s = *(const s16x8*)&sh.w.Abuf[cur][lr][kt * 32 + q * 8];
        #pragma unroll
        for (int nt = 0; nt < 4; ++nt)
          acc[nt] = __builtin_amdgcn_mfma_f32_16x16x32_bf16(a.b, bfrag[nt][kt].b, acc[nt], 0, 0, 0);
      }
      int gidx = c * 8 + gi;
      #pragma unroll
      for (int nt = 0; nt < 4; ++nt) {
        float r0 = acc[nt][0], r1 = acc[nt][1], r2 = acc[nt][2], r3 = acc[nt][3];
        float mx = fmaxf(fmaxf(r0, r1), fmaxf(r2, r3));
        float mn = fminf(fminf(r0, r1), fminf(r2, r3));
        sum1[nt] += r0 + r1 + r2 + r3;
        sum2[nt] += r0 * r0 + r1 * r1 + r2 * r2 + r3 * r3;
        mx = fmaxf(mx, __shfl_xor(mx, 16)); mn = fminf(mn, __shfl_xor(mn, 16));
        mx = fmaxf(mx, __shfl_xor(mx, 32)); mn = fminf(mn, __shfl_xor(mn, 32));
        if (q == 0) {
          int col = w * 64 + nt * 16 + lr;
          wmax[(size_t)gidx * DOUT_CH + col] = mx;
          wmin[(size_t)gidx * DOUT_CH + col] = mn;
        }
      }
      __syncthreads();
    }
  }

  // per-worker channel partials
  #pragma unroll
  for (int nt = 0; nt < 4; ++nt) {
    float s1 = sum1[nt], s2 = sum2[nt];
    s1 += __shfl_xor(s1, 16); s2 += __shfl_xor(s2, 16);
    s1 += __shfl_xor(s1, 32); s2 += __shfl_xor(s2, 32);
    if (q == 0) {
      int col = w * 64 + nt * 16 + lr;
      psum[(size_t)col * NWORKERS + wi]   = s1;
      psumsq[(size_t)col * NWORKERS + wi] = s2;
    }
  }
}

// K4: reduce partials -> per-channel scale/shift (bias cancels in train BN)
__global__ __launch_bounds__(256)
void stats_kernel(const float* __restrict__ psum, const float* __restrict__ psumsq,
                  const float* __restrict__ gamma, const float* __restrict__ beta,
                  float* __restrict__ sc, float* __restrict__ tc)
{
  const int c = blockIdx.x;
  const int tid = threadIdx.x, lane = tid & 63, w = tid >> 6;
  float s1 = 0.f, s2 = 0.f;
  for (int r = tid; r < NWORKERS; r += 256) {
    s1 += psum[(size_t)c * NWORKERS + r];
    s2 += psumsq[(size_t)c * NWORKERS + r];
  }
  #pragma unroll
  for (int off = 1; off < 64; off <<= 1) { s1 += __shfl_xor(s1, off); s2 += __shfl_xor(s2, off); }
  __shared__ float a1[4], a2[4];
  if (lane == 0) { a1[w] = s1; a2[w] = s2; }
  __syncthreads();
  if (tid == 0) {
    float S1 = a1[0] + a1[1] + a1[2] + a1[3];
    float S2 = a2[0] + a2[1] + a2[2] + a2[3];
    const float inv = 1.0f / (float)MROWS;
    float mean = S1 * inv;
    float var  = S2 * inv - mean * mean;
    float rs = rsqrtf(var + 1e-5f);
    float s = gamma[c] * rs;
    sc[c] = s;
    tc[c] = beta[c] - mean * s;
  }
}

// K5: out = relu(s * (s>0 ? max : min) + t)
__global__ __launch_bounds__(256)
void final_kernel(const float* __restrict__ wmax, const float* __restrict__ wmin,
                  const float* __restrict__ sc, const float* __restrict__ tc,
                  float* __restrict__ out)
{
  int i4 = blockIdx.x * 256 + threadIdx.x;
  int base = i4 * 4;
  int c = base & (DOUT_CH - 1);
  float4 mx = *(const float4*)(wmax + base);
  float4 mn = *(const float4*)(wmin + base);
  float4 sv = *(const float4*)(sc + c);
  float4 tv = *(const float4*)(tc + c);
  float4 o;
  o.x = fmaxf(fmaf(sv.x, (sv.x > 0.f ? mx.x : mn.x), tv.x), 0.f);
  o.y = fmaxf(fmaf(sv.y, (sv.y > 0.f ? mx.y : mn.y), tv.y), 0.f);
  o.z = fmaxf(fmaf(sv.z, (sv.z > 0.f ? mx.z : mn.z), tv.z), 0.f);
  o.w = fmaxf(fmaf(sv.w, (sv.w > 0.f ? mx.w : mn.w), tv.w), 0.f);
  *(float4*)(out + base) = o;
}

extern "C" void kernel_launch(void* const* d_in, const int* in_sizes, int n_in,
                              void* d_out, int out_size, void* d_ws, size_t ws_size,
                              hipStream_t stream)
{
  const float* feature = (const float*)d_in[0];
  const float* coord   = (const float*)d_in[1];
  const float* W       = (const float*)d_in[2];
  // d_in[3] = conv bias: cancels exactly in train-mode BN -> unused
  const float* gamma   = (const float*)d_in[4];
  const float* beta    = (const float*)d_in[5];
  float* out = (float*)d_out;
  float* out_coord = out + OUT_FEAT_ELEMS;

  char* ws = (char*)d_ws;
  int*            flags  = (int*)(ws + 0);                      // progress[16] + wb_ready
  unsigned short* Wb     = (unsigned short*)(ws + 4096);        // 80 KB
  float*          psum   = (float*)(ws + (1 << 20));            // 256*240*4 = 240 KB
  float*          psumsq = (float*)(ws + (2 << 20));            // 240 KB
  float*          sc     = (float*)(ws + (3 << 20));            // 1 KB
  float*          tc     = (float*)(ws + (3 << 20) + 4096);     // 1 KB
  float*          wmax   = (float*)(ws + (8 << 20));            // 16 MB
  float*          wmin   = (float*)(ws + (8 << 20) + (size_t)OUT_FEAT_ELEMS * 4); // 16 MB
  int* progress = flags;
  int* wb_ready = flags + 16;

  // zero the sync flags (workspace is re-poisoned to 0xAA before every call)
  hipMemsetAsync(flags, 0, 128, stream);

  hipLaunchKernelGGL(fused_kernel, dim3(BATCH + NWORKERS), dim3(256), 0, stream,
                     feature, coord, W, out_coord, Wb,
                     psum, psumsq, wmax, wmin, progress, wb_ready);
  hipLaunchKernelGGL(stats_kernel, dim3(DOUT_CH), dim3(256), 0, stream,
                     psum, psumsq, gamma, beta, sc, tc);
  hipLaunchKernelGGL(final_kernel, dim3(OUT_FEAT_ELEMS / 1024), dim3(256), 0, stream,
                     wmax, wmin, sc, tc, out);
}

// Round 7
// 799.411 us; speedup vs baseline: 1.3777x; 1.3777x over previous
//
#include <hip/hip_runtime.h>
#include <stdint.h>

// Problem constants
#define BATCH 16
#define NPTS 4096
#define DFEAT 128
#define NGRP 1024
#define KNNK 16
#define DOUT_CH 256
#define KPAD 160          // 131 padded to 5*32 for MFMA K
#define APAD 168          // LDS row stride (pad for banks)
#define NGROUPS (BATCH*NGRP)            // 16384
#define MROWS (NGROUPS*KNNK)            // 262144
#define NWORKERS 240
#define NCHUNKS (NGROUPS/8)             // 2048 chunks of 8 groups
#define CHUNKS_PER_BATCH (NGRP/8)       // 128
#define OUT_FEAT_ELEMS (NGROUPS*DOUT_CH) // 4194304
#define KNN_SLOTS 512
#define PROG_STRIDE 16                  // ints; one 64B cacheline per batch flag

typedef __attribute__((ext_vector_type(8))) short s16x8;
typedef __attribute__((ext_vector_type(8))) __bf16 bf16x8;
typedef __attribute__((ext_vector_type(4))) float f32x4;

union V8U { s16x8 s; bf16x8 b; };

__device__ inline unsigned short f2bf(float f) {
  unsigned u = __float_as_uint(f);
  unsigned r = 0x7FFFu + ((u >> 16) & 1u);
  return (unsigned short)((u + r) >> 16);
}

// Bit-exact (vs fp32 numpy ref, no-FMA) squared distance: ((dx*dx + dy*dy) + dz*dz)
__device__ inline float sqdist3(float ax, float ay, float az,
                                float bx, float by, float bz) {
  float dx = __fsub_rn(ax, bx);
  float dy = __fsub_rn(ay, by);
  float dz = __fsub_rn(az, bz);
  return __fadd_rn(__fadd_rn(__fmul_rn(dx, dx), __fmul_rn(dy, dy)), __fmul_rn(dz, dz));
}

__device__ inline unsigned long long u64max(unsigned long long a, unsigned long long b) {
  return a > b ? a : b;
}

// DPP max step (bound_ctrl=true: invalid lanes read 0; 0 never wins a max of keys>0)
template<int CTRL>
__device__ inline unsigned long long dpp_max_step(unsigned long long k) {
  unsigned hi = (unsigned)(k >> 32), lo = (unsigned)k;
  unsigned hi2 = (unsigned)__builtin_amdgcn_update_dpp(0, (int)hi, CTRL, 0xF, 0xF, true);
  unsigned lo2 = (unsigned)__builtin_amdgcn_update_dpp(0, (int)lo, CTRL, 0xF, 0xF, true);
  unsigned long long k2 = ((unsigned long long)hi2 << 32) | lo2;
  return k2 > k ? k2 : k;
}
__device__ inline unsigned long long wave_max_u64(unsigned long long k) {
  k = dpp_max_step<0xB1>(k);
  k = dpp_max_step<0x4E>(k);
  k = dpp_max_step<0x141>(k);
  k = dpp_max_step<0x140>(k);
  k = dpp_max_step<0x142>(k);
  k = dpp_max_step<0x143>(k);
  return k;   // lane 63 holds max
}

// DPP min step (bound_ctrl=false, old=self: invalid lanes keep own key -> harmless for min)
template<int CTRL>
__device__ inline unsigned long long dpp_min_step(unsigned long long k) {
  unsigned hi = (unsigned)(k >> 32), lo = (unsigned)k;
  unsigned hi2 = (unsigned)__builtin_amdgcn_update_dpp((int)hi, (int)hi, CTRL, 0xF, 0xF, false);
  unsigned lo2 = (unsigned)__builtin_amdgcn_update_dpp((int)lo, (int)lo, CTRL, 0xF, 0xF, false);
  unsigned long long k2 = ((unsigned long long)hi2 << 32) | lo2;
  return k2 < k ? k2 : k;
}
__device__ inline unsigned long long wave_min_u64(unsigned long long k) {
  k = dpp_min_step<0xB1>(k);
  k = dpp_min_step<0x4E>(k);
  k = dpp_min_step<0x141>(k);
  k = dpp_min_step<0x140>(k);
  k = dpp_min_step<0x142>(k);
  k = dpp_min_step<0x143>(k);
  return k;   // lane 63 holds min
}

// Shared-memory union: FPS role vs worker role. ~93 KB both paths =>
// strictly 1 block/CU, 256 blocks <= 256 CUs, all resident.
struct FpsSh {
  float4 c4[NPTS];                 // 64 KB
  float ocb[NGRP * 3];             // 12 KB
  unsigned long long slots[2][4];  // double-buffered per-wave winners
};
struct WrkSh {
  float wd[4][NPTS];               // 64 KB per-wave dist caches
  float svd[4][KNN_SLOTS];         // 8 KB
  int   svi[4][KNN_SLOTS];         // 8 KB
  unsigned short Abuf[2][16][APAD];// 10.5 KB
  int   nidx_s[8][KNNK];           // 512 B
  float cent_s[8][3];              // staged centers
};
union ShU { FpsSh f; WrkSh w; };

// ---------------------------------------------------------------------------
// Fused producer-consumer kernel.
// Blocks 0..15: FPS per batch; publish centers in chunks of 8.
// Blocks 16..255: workers claim chunks in AVAILABILITY order:
//   ord = wi + 240k, b = ord & 15, lc = ord >> 4  (lc monotone per worker,
//   all batches progress at the same rate -> no head-of-line blocking).
// ---------------------------------------------------------------------------
__global__ __launch_bounds__(256)
void fused_kernel(const float* __restrict__ feat, const float* __restrict__ coord,
                  const float* __restrict__ W, float* __restrict__ out_coord,
                  unsigned short* __restrict__ Wb,
                  float* __restrict__ psum, float* __restrict__ psumsq,
                  float* __restrict__ wmax, float* __restrict__ wmin,
                  int* __restrict__ progress, int* __restrict__ wb_ready)
{
  __shared__ ShU sh;
  const int tid = threadIdx.x;
  const int w = tid >> 6;
  const int lane = tid & 63;

  if (blockIdx.x < BATCH) {
    // ------------------------- FPS producer role -------------------------
    const int b = blockIdx.x;
    float4* c4 = sh.f.c4;
    float* ocb = sh.f.ocb;

    const float* g = coord + (size_t)b * NPTS * 3;
    for (int p = tid; p < NPTS; p += 256)
      c4[p] = make_float4(g[3 * p], g[3 * p + 1], g[3 * p + 2], 0.f);
    __syncthreads();

    float px[16], py[16], pz[16], dist[16];
    unsigned lokey[16];
    #pragma unroll
    for (int j = 0; j < 16; ++j) {
      int p = tid + 256 * j;
      float4 c = c4[p];
      px[j] = c.x; py[j] = c.y; pz[j] = c.z;
      dist[j] = __builtin_inff();
      lokey[j] = 0xFFFFFFFFu - (unsigned)p;      // bigger lo == smaller idx
    }

    float lx = c4[0].x, ly = c4[0].y, lz = c4[0].z;
    if (tid == 0) { ocb[0] = lx; ocb[1] = ly; ocb[2] = lz; }

    float* oc = out_coord + (size_t)b * NGRP * 3;
    int pend = 0;

    for (int i = 1; i < NGRP; ++i) {
      const int par = i & 1;
      unsigned long long cand[16];
      #pragma unroll
      for (int j = 0; j < 16; ++j) {
        float d  = sqdist3(px[j], py[j], pz[j], lx, ly, lz);
        float nd = fminf(dist[j], d);
        dist[j] = nd;
        cand[j] = ((unsigned long long)__float_as_uint(nd) << 32) | lokey[j];
      }
      #pragma unroll
      for (int st = 8; st >= 1; st >>= 1)
        #pragma unroll
        for (int j = 0; j < st; ++j)
          cand[j] = u64max(cand[j], cand[j + st]);
      unsigned long long best = wave_max_u64(cand[0]);
      if (lane == 63) sh.f.slots[par][w] = best;
      __syncthreads();

      // publish: stores issued 1 iter ago are drained by the barrier above
      if (pend) {
        if (tid == 0) {
          __threadfence();
          __hip_atomic_store(&progress[b * PROG_STRIDE], pend, __ATOMIC_RELEASE, __HIP_MEMORY_SCOPE_AGENT);
        }
        pend = 0;
      }
      if ((i & 7) == 0) {                    // i = 8,16,...,1016
        if (tid < 24) oc[(i - 8) * 3 + tid] = ocb[(i - 8) * 3 + tid];
        pend = i;
      }

      unsigned long long s0 = u64max(sh.f.slots[par][0], sh.f.slots[par][1]);
      unsigned long long s1 = u64max(sh.f.slots[par][2], sh.f.slots[par][3]);
      unsigned long long f = u64max(s0, s1);
      int mi = (int)(0xFFFFFFFFu - (unsigned)(f & 0xFFFFFFFFull));

      float4 cw = c4[mi];
      lx = cw.x; ly = cw.y; lz = cw.z;
      if (tid < 3) ocb[3 * i + tid] = (tid == 0) ? cw.x : ((tid == 1) ? cw.y : cw.z);
    }

    __syncthreads();
    #pragma unroll
    for (int qq = 0; qq < 12; ++qq) oc[tid + 256 * qq] = ocb[tid + 256 * qq];
    __syncthreads();
    if (tid == 0) {
      __threadfence();
      __hip_atomic_store(&progress[b * PROG_STRIDE], NGRP, __ATOMIC_RELEASE, __HIP_MEMORY_SCOPE_AGENT);
    }
    return;
  }

  // --------------------------- worker role ---------------------------
  const int wi = blockIdx.x - BATCH;

  if (wi == 0) {
    // W: [256][131] fp32 -> Wb: [256][160] bf16 (cols 0..127 = W[:,3:131],
    // 128..130 = W[:,0:3], 131..159 = 0)
    for (int i = tid; i < DOUT_CH * KPAD; i += 256) {
      int n = i / KPAD;
      int k = i - n * KPAD;
      float v = 0.f;
      if (k < 128)      v = W[n * 131 + 3 + k];
      else if (k < 131) v = W[n * 131 + (k - 128)];
      Wb[i] = f2bf(v);
    }
    __syncthreads();
    if (tid == 0) {
      __threadfence();
      __hip_atomic_store(wb_ready, 1, __ATOMIC_RELEASE, __HIP_MEMORY_SCOPE_AGENT);
    }
  }
  // wait for Wb
  if (tid == 0) {
    while (__hip_atomic_load(wb_ready, __ATOMIC_RELAXED, __HIP_MEMORY_SCOPE_AGENT) == 0)
      __builtin_amdgcn_s_sleep(1);
    __threadfence();
  }
  __syncthreads();

  const int lr = lane & 15, q = lane >> 4;

  // B fragments in registers (held across all chunks)
  V8U bfrag[4][5];
  #pragma unroll
  for (int nt = 0; nt < 4; ++nt)
    #pragma unroll
    for (int kt = 0; kt < 5; ++kt) {
      int n = w * 64 + nt * 16 + lr;
      bfrag[nt][kt].s = *(const s16x8*)(Wb + n * KPAD + kt * 32 + q * 8);
    }

  // zero pad cols 128..159 of both Abuf buffers once
  for (int i = tid; i < 2 * 16 * 32; i += 256) {
    int buf = i >> 9, rr = (i >> 5) & 15, cc = 128 + (i & 31);
    sh.w.Abuf[buf][rr][cc] = 0;
  }
  float sum1[4] = {0, 0, 0, 0}, sum2[4] = {0, 0, 0, 0};
  __syncthreads();

  for (int ord = wi; ord < NCHUNKS; ord += NWORKERS) {
    const int b  = ord & 15;            // availability-ordered claim
    const int lc = ord >> 4;
    const int need = lc * 8 + 8;

    if (tid == 0) {
      while (__hip_atomic_load(&progress[b * PROG_STRIDE], __ATOMIC_RELAXED, __HIP_MEMORY_SCOPE_AGENT) < need)
        __builtin_amdgcn_s_sleep(16);
      __threadfence();                  // acquire: invalidate caches
    }
    __syncthreads();

    // stage the 8 centers of this chunk
    if (tid < 24) sh.w.cent_s[tid / 3][tid % 3] =
        out_coord[(size_t)b * NGRP * 3 + lc * 24 + tid];
    __syncthreads();

    // ---- kNN (wave-local, no block barriers): wave w does centers 2w, 2w+1
    const float* pc = coord + (size_t)b * NPTS * 3;
    for (int k2 = 0; k2 < 2; ++k2) {
      const int k8 = w * 2 + k2;
      const float cx = sh.w.cent_s[k8][0], cy = sh.w.cent_s[k8][1], cz = sh.w.cent_s[k8][2];
      float* wd  = sh.w.wd[w];
      float* wsd = sh.w.svd[w];
      int*   wsi = sh.w.svi[w];

      float m = __builtin_inff();
      for (int tt = 0; tt < 64; ++tt) {
        int p = tt * 64 + lane;
        float d = sqdist3(cx, cy, cz, pc[3 * p], pc[3 * p + 1], pc[3 * p + 2]);
        wd[p] = d;
        m = fminf(m, d);
      }
      // T = 16th-smallest of per-lane minima (upper bound on true 16th dist)
      unsigned mb = __float_as_uint(m);
      unsigned prefix = 0u;
      for (int bit = 30; bit >= 0; --bit) {
        unsigned trial = prefix | (1u << bit);
        if (__popcll(__ballot(mb < trial)) < 16) prefix = trial;
      }
      const unsigned T = prefix;

      // compact survivors (slot order == ascending point idx)
      int base = 0;
      unsigned long long ltmask = (1ull << lane) - 1ull;
      for (int tt = 0; tt < 64; ++tt) {
        int p = tt * 64 + lane;
        float d = wd[p];
        bool keep = (__float_as_uint(d) <= T);
        unsigned long long mk = __ballot(keep);
        if (keep) {
          int pos = base + __popcll(mk & ltmask);
          if (pos < KNN_SLOTS) { wsd[pos] = d; wsi[pos] = p; }
        }
        base += __popcll(mk);
      }
      int S = base < KNN_SLOTS ? base : KNN_SLOTS;

      // register-resident survivors: lane owns slots lane+64k
      float rsd[8];
      #pragma unroll
      for (int k = 0; k < 8; ++k) {
        int s = lane + 64 * k;
        rsd[k] = (s < S) ? wsd[s] : __builtin_inff();
      }
      // 16 exact argmin rounds; u64-min key = (dbits<<32)|slot (lowest idx tie-break)
      for (int r = 0; r < KNNK; ++r) {
        unsigned long long key = 0xFFFFFFFFFFFFFFFFull;
        #pragma unroll
        for (int k = 0; k < 8; ++k) {
          unsigned long long kk = ((unsigned long long)__float_as_uint(rsd[k]) << 32)
                                | (unsigned)(lane + 64 * k);
          key = kk < key ? kk : key;
        }
        key = wave_min_u64(key);
        int bs = __builtin_amdgcn_readlane((int)(unsigned)(key & 0xFFFFFFFFull), 63);
        #pragma unroll
        for (int k = 0; k < 8; ++k)
          if (lane == (bs & 63) && k == (bs >> 6)) rsd[k] = __builtin_inff();
        if (lane == 0) sh.w.nidx_s[k8][r] = wsi[bs];
      }
    }
    __syncthreads();

    // ---- GEMM for the 8 groups of this chunk
    auto stage = [&](int gi, int buf) {
      int r = tid >> 4, c16 = tid & 15;
      int np = sh.w.nidx_s[gi][r];
      const float* fr = feat + ((size_t)(b * NPTS + np)) * DFEAT + c16 * 8;
      float4 f0 = ((const float4*)fr)[0];
      float4 f1 = ((const float4*)fr)[1];
      s16x8 v;
      v[0] = f2bf(f0.x); v[1] = f2bf(f0.y); v[2] = f2bf(f0.z); v[3] = f2bf(f0.w);
      v[4] = f2bf(f1.x); v[5] = f2bf(f1.y); v[6] = f2bf(f1.z); v[7] = f2bf(f1.w);
      *(s16x8*)&sh.w.Abuf[buf][r][c16 * 8] = v;
      if (tid < 16) {
        int np2 = sh.w.nidx_s[gi][tid];
        const float* p = coord + ((size_t)(b * NPTS + np2)) * 3;
        sh.w.Abuf[buf][tid][128] = f2bf(p[0] - sh.w.cent_s[gi][0]);
        sh.w.Abuf[buf][tid][129] = f2bf(p[1] - sh.w.cent_s[gi][1]);
        sh.w.Abuf[buf][tid][130] = f2bf(p[2] - sh.w.cent_s[gi][2]);
      }
    };

    stage(0, 0);
    __syncthreads();

    for (int gi = 0; gi < 8; ++gi) {
      int cur = gi & 1;
      if (gi < 7) stage(gi + 1, cur ^ 1);

      f32x4 acc[4];
      #pragma unroll
      for (int nt = 0; nt < 4; ++nt) acc[nt] = (f32x4)0.0f;
      #pragma unroll
      for (int kt = 0; kt < 5; ++kt) {
        V8U a;
        a.s = *(const s16x8*)&sh.w.Abuf[cur][lr][kt * 32 + q * 8];
        #pragma unroll
        for (int nt = 0; nt < 4; ++nt)
          acc[nt] = __builtin_amdgcn_mfma_f32_16x16x32_bf16(a.b, bfrag[nt][kt].b, acc[nt], 0, 0, 0);
      }
      int gidx = (b * CHUNKS_PER_BATCH + lc) * 8 + gi;
      #pragma unroll
      for (int nt = 0; nt < 4; ++nt) {
        float r0 = acc[nt][0], r1 = acc[nt][1], r2 = acc[nt][2], r3 = acc[nt][3];
        float mx = fmaxf(fmaxf(r0, r1), fmaxf(r2, r3));
        float mn = fminf(fminf(r0, r1), fminf(r2, r3));
        sum1[nt] += r0 + r1 + r2 + r3;
        sum2[nt] += r0 * r0 + r1 * r1 + r2 * r2 + r3 * r3;
        mx = fmaxf(mx, __shfl_xor(mx, 16)); mn = fminf(mn, __shfl_xor(mn, 16));
        mx = fmaxf(mx, __shfl_xor(mx, 32)); mn = fminf(mn, __shfl_xor(mn, 32));
        if (q == 0) {
          int col = w * 64 + nt * 16 + lr;
          wmax[(size_t)gidx * DOUT_CH + col] = mx;
          wmin[(size_t)gidx * DOUT_CH + col] = mn;
        }
      }
      __syncthreads();
    }
  }

  // per-worker channel partials
  #pragma unroll
  for (int nt = 0; nt < 4; ++nt) {
    float s1 = sum1[nt], s2 = sum2[nt];
    s1 += __shfl_xor(s1, 16); s2 += __shfl_xor(s2, 16);
    s1 += __shfl_xor(s1, 32); s2 += __shfl_xor(s2, 32);
    if (q == 0) {
      int col = w * 64 + nt * 16 + lr;
      psum[(size_t)col * NWORKERS + wi]   = s1;
      psumsq[(size_t)col * NWORKERS + wi] = s2;
    }
  }
}

// K4: reduce partials -> per-channel scale/shift (bias cancels in train BN)
__global__ __launch_bounds__(256)
void stats_kernel(const float* __restrict__ psum, const float* __restrict__ psumsq,
                  const float* __restrict__ gamma, const float* __restrict__ beta,
                  float* __restrict__ sc, float* __restrict__ tc)
{
  const int c = blockIdx.x;
  const int tid = threadIdx.x, lane = tid & 63, w = tid >> 6;
  float s1 = 0.f, s2 = 0.f;
  for (int r = tid; r < NWORKERS; r += 256) {
    s1 += psum[(size_t)c * NWORKERS + r];
    s2 += psumsq[(size_t)c * NWORKERS + r];
  }
  #pragma unroll
  for (int off = 1; off < 64; off <<= 1) { s1 += __shfl_xor(s1, off); s2 += __shfl_xor(s2, off); }
  __shared__ float a1[4], a2[4];
  if (lane == 0) { a1[w] = s1; a2[w] = s2; }
  __syncthreads();
  if (tid == 0) {
    float S1 = a1[0] + a1[1] + a1[2] + a1[3];
    float S2 = a2[0] + a2[1] + a2[2] + a2[3];
    const float inv = 1.0f / (float)MROWS;
    float mean = S1 * inv;
    float var  = S2 * inv - mean * mean;
    float rs = rsqrtf(var + 1e-5f);
    float s = gamma[c] * rs;
    sc[c] = s;
    tc[c] = beta[c] - mean * s;
  }
}

// K5: out = relu(s * (s>0 ? max : min) + t)
__global__ __launch_bounds__(256)
void final_kernel(const float* __restrict__ wmax, const float* __restrict__ wmin,
                  const float* __restrict__ sc, const float* __restrict__ tc,
                  float* __restrict__ out)
{
  int i4 = blockIdx.x * 256 + threadIdx.x;
  int base = i4 * 4;
  int c = base & (DOUT_CH - 1);
  float4 mx = *(const float4*)(wmax + base);
  float4 mn = *(const float4*)(wmin + base);
  float4 sv = *(const float4*)(sc + c);
  float4 tv = *(const float4*)(tc + c);
  float4 o;
  o.x = fmaxf(fmaf(sv.x, (sv.x > 0.f ? mx.x : mn.x), tv.x), 0.f);
  o.y = fmaxf(fmaf(sv.y, (sv.y > 0.f ? mx.y : mn.y), tv.y), 0.f);
  o.z = fmaxf(fmaf(sv.z, (sv.z > 0.f ? mx.z : mn.z), tv.z), 0.f);
  o.w = fmaxf(fmaf(sv.w, (sv.w > 0.f ? mx.w : mn.w), tv.w), 0.f);
  *(float4*)(out + base) = o;
}

extern "C" void kernel_launch(void* const* d_in, const int* in_sizes, int n_in,
                              void* d_out, int out_size, void* d_ws, size_t ws_size,
                              hipStream_t stream)
{
  const float* feature = (const float*)d_in[0];
  const float* coord   = (const float*)d_in[1];
  const float* W       = (const float*)d_in[2];
  // d_in[3] = conv bias: cancels exactly in train-mode BN -> unused
  const float* gamma   = (const float*)d_in[4];
  const float* beta    = (const float*)d_in[5];
  float* out = (float*)d_out;
  float* out_coord = out + OUT_FEAT_ELEMS;

  char* ws = (char*)d_ws;
  int*            flags  = (int*)(ws + 0);                      // progress[16*16] + wb_ready
  unsigned short* Wb     = (unsigned short*)(ws + 4096);        // 80 KB
  float*          psum   = (float*)(ws + (1 << 20));            // 256*240*4 = 240 KB
  float*          psumsq = (float*)(ws + (2 << 20));            // 240 KB
  float*          sc     = (float*)(ws + (3 << 20));            // 1 KB
  float*          tc     = (float*)(ws + (3 << 20) + 4096);     // 1 KB
  float*          wmax   = (float*)(ws + (8 << 20));            // 16 MB
  float*          wmin   = (float*)(ws + (8 << 20) + (size_t)OUT_FEAT_ELEMS * 4); // 16 MB
  int* progress = flags;                 // stride PROG_STRIDE (64 B) per batch
  int* wb_ready = flags + BATCH * PROG_STRIDE;

  // zero the sync flags (workspace is re-poisoned to 0xAA before every call)
  hipMemsetAsync(flags, 0, (BATCH * PROG_STRIDE + 16) * sizeof(int), stream);

  hipLaunchKernelGGL(fused_kernel, dim3(BATCH + NWORKERS), dim3(256), 0, stream,
                     feature, coord, W, out_coord, Wb,
                     psum, psumsq, wmax, wmin, progress, wb_ready);
  hipLaunchKernelGGL(stats_kernel, dim3(DOUT_CH), dim3(256), 0, stream,
                     psum, psumsq, gamma, beta, sc, tc);
  hipLaunchKernelGGL(final_kernel, dim3(OUT_FEAT_ELEMS / 1024), dim3(256), 0, stream,
                     wmax, wmin, sc, tc, out);
}